// Round 5
// baseline (514.329 us; speedup 1.0000x reference)
//
#include <hip/hip_runtime.h>
#include <math.h>

#define BB 64
#define NN 4096
#define DD 256

// ---------------------------------------------------------------------------
// F-pass: for a chunk of rows, compute b[n] += m[n]*dot(s, x[n]) and
// accumulate per-wave online-softmax partials (M, Z, and optionally the
// exp-weighted partial sigma vector) for the NEXT iteration's weighted sum.
// Each wave owns rowsPerWave consecutive rows; lane i owns columns 4i..4i+3.
// Rows processed in groups of 4: 4 independent loads + 4 parallel butterfly
// chains in flight; online-softmax update is branchless (no exec-mask CF in
// the hot loop -> compiler can software-pipeline the global loads).
// FINAL: logits = b (final softmax), no sigma accumulation.
// ---------------------------------------------------------------------------
template<bool FINAL>
__global__ __launch_bounds__(256) void fpass_kernel(
    const float* __restrict__ x, const float* __restrict__ m,
    const float* __restrict__ s_buf, float* __restrict__ b_buf,
    float* __restrict__ part_sig, float* __restrict__ part_M,
    float* __restrict__ part_Z, int P, int rowsPerWave)
{
    const int lane = threadIdx.x & 63;
    const int wib  = threadIdx.x >> 6;        // wave in block (4 waves/block)
    const int bpb  = P >> 2;                  // blocks per batch
    const int batch = blockIdx.x / bpb;
    const int p = (blockIdx.x % bpb) * 4 + wib;
    const int n0 = p * rowsPerWave;

    const float4 s4 = reinterpret_cast<const float4*>(s_buf + batch * DD)[lane];
    const float4* __restrict__ xr =
        reinterpret_cast<const float4*>(x + ((size_t)batch * NN + n0) * DD) + lane;
    const float* __restrict__ mrow = m + (size_t)batch * NN + n0;
    float* __restrict__ brow = b_buf + (size_t)batch * NN + n0;

    float M = -INFINITY, Z = 0.f;
    float sx = 0.f, sy = 0.f, sz = 0.f, sw = 0.f;

    // branchless online-softmax step (l is wave-uniform; math is exact even
    // on the first row: M=-inf -> c=exp(-inf)=0)
    auto upd = [&](float bn, float mn, const float4& xv) {
        float l = FINAL ? bn : mn * bn;
        float newM = fmaxf(M, l);
        float c = __expf(M - newM);
        float e = __expf(l - newM);
        Z = Z * c + e;
        if (!FINAL) {
            float wgt = e * mn;
            sx = sx * c + wgt * xv.x;
            sy = sy * c + wgt * xv.y;
            sz = sz * c + wgt * xv.z;
            sw = sw * c + wgt * xv.w;
        }
        M = newM;
    };

    for (int r0 = 0; r0 < rowsPerWave; r0 += 4) {
        float4 xv0 = xr[(size_t)(r0 + 0) * (DD / 4)];
        float4 xv1 = xr[(size_t)(r0 + 1) * (DD / 4)];
        float4 xv2 = xr[(size_t)(r0 + 2) * (DD / 4)];
        float4 xv3 = xr[(size_t)(r0 + 3) * (DD / 4)];
        const float4 m4 = *reinterpret_cast<const float4*>(mrow + r0);
        const float4 b4 = *reinterpret_cast<const float4*>(brow + r0);

        float dp0 = xv0.x * s4.x + xv0.y * s4.y + xv0.z * s4.z + xv0.w * s4.w;
        float dp1 = xv1.x * s4.x + xv1.y * s4.y + xv1.z * s4.z + xv1.w * s4.w;
        float dp2 = xv2.x * s4.x + xv2.y * s4.y + xv2.z * s4.z + xv2.w * s4.w;
        float dp3 = xv3.x * s4.x + xv3.y * s4.y + xv3.z * s4.z + xv3.w * s4.w;
        #pragma unroll
        for (int off = 32; off; off >>= 1) {
            dp0 += __shfl_xor(dp0, off, 64);
            dp1 += __shfl_xor(dp1, off, 64);
            dp2 += __shfl_xor(dp2, off, 64);
            dp3 += __shfl_xor(dp3, off, 64);
        }
        float bn0 = b4.x + m4.x * dp0;        // b += m_n * (s . x_n)
        float bn1 = b4.y + m4.y * dp1;
        float bn2 = b4.z + m4.z * dp2;
        float bn3 = b4.w + m4.w * dp3;
        if (lane == 0)
            *reinterpret_cast<float4*>(brow + r0) = make_float4(bn0, bn1, bn2, bn3);
        upd(bn0, m4.x, xv0);
        upd(bn1, m4.y, xv1);
        upd(bn2, m4.z, xv2);
        upd(bn3, m4.w, xv3);
    }
    if (!FINAL) {
        reinterpret_cast<float4*>(part_sig + ((size_t)batch * P + p) * DD)[lane] =
            make_float4(sx, sy, sz, sw);
    }
    if (lane == 0) {
        part_M[batch * P + p] = M;
        part_Z[batch * P + p] = Z;
    }
}

// ---------------------------------------------------------------------------
// Reduce: combine P wave-partials of one batch with max-rescaling.
// Wave 0 reduces M/Z via shuffles; then 1024 threads split the p-loop 4-way
// (tid = q*256 + d) so only P/4 serial strided loads per thread.
// !FINAL: sigma = (sum_p c_p * part_sig_p)/Z, squash -> s_buf (and s_out).
// FINAL:  just write (Mg, Zg) for the final softmax.
// ---------------------------------------------------------------------------
template<bool FINAL>
__global__ __launch_bounds__(1024) void reduce_kernel(
    const float* __restrict__ part_sig, const float* __restrict__ part_M,
    const float* __restrict__ part_Z, float* __restrict__ s_buf,
    float* __restrict__ s_out, float* __restrict__ MZf, int P)
{
    const int b = blockIdx.x;
    const int tid = threadIdx.x;
    __shared__ float red[1024];
    __shared__ float csh[128];
    __shared__ float mg_sh, zg_sh;

    if (tid < 64) {
        float M0 = (tid < P) ? part_M[b * P + tid] : -INFINITY;
        float M1 = (tid + 64 < P) ? part_M[b * P + tid + 64] : -INFINITY;
        float Mm = fmaxf(M0, M1);
        #pragma unroll
        for (int off = 32; off; off >>= 1) Mm = fmaxf(Mm, __shfl_xor(Mm, off, 64));
        float c0 = (tid < P) ? expf(M0 - Mm) : 0.f;
        float c1 = (tid + 64 < P) ? expf(M1 - Mm) : 0.f;
        if (tid < P) csh[tid] = c0;
        if (tid + 64 < P) csh[tid + 64] = c1;
        float Zs = ((tid < P) ? part_Z[b * P + tid] : 0.f) * c0
                 + ((tid + 64 < P) ? part_Z[b * P + tid + 64] : 0.f) * c1;
        #pragma unroll
        for (int off = 32; off; off >>= 1) Zs += __shfl_xor(Zs, off, 64);
        if (tid == 0) { mg_sh = Mm; zg_sh = Zs; }
    }
    __syncthreads();

    if (FINAL) {
        if (tid == 0) { MZf[2 * b] = mg_sh; MZf[2 * b + 1] = zg_sh; }
        return;
    }

    const int q = tid >> 8;       // 0..3: p-residue class
    const int d = tid & 255;      // feature dim
    float sig = 0.f;
    #pragma unroll 4
    for (int k = q; k < P; k += 4)
        sig += csh[k] * part_sig[((size_t)b * P + k) * DD + d];
    red[tid] = sig;
    __syncthreads();

    if (tid < 256) {
        sig = red[tid] + red[tid + 256] + red[tid + 512] + red[tid + 768];
        sig /= zg_sh;
        red[tid] = sig * sig;
    }
    __syncthreads();
    for (int s = 128; s > 0; s >>= 1) {
        if (tid < s) red[tid] += red[tid + s];
        __syncthreads();
    }
    if (tid < 256) {
        float n2 = red[0];
        float nrm = sqrtf(n2);
        float scale = n2 / (1.f + n2) / (nrm + 1e-8f);   // squash
        float sv = scale * sig;
        s_buf[b * DD + tid] = sv;
        if (s_out) s_out[b * DD + tid] = sv;
    }
}

// ---------------------------------------------------------------------------
// Final w = exp(b - M)/Z  (softmax over N, logits = b), float4-vectorized.
// ---------------------------------------------------------------------------
__global__ __launch_bounds__(256) void w_kernel(
    const float* __restrict__ b_buf, const float* __restrict__ MZf,
    float* __restrict__ w_out)
{
    int i = blockIdx.x * 256 + threadIdx.x;   // over B*N/4 float4s
    int b = i >> 10;                          // N/4 = 1024 float4 per batch
    float Mg = MZf[2 * b];
    float iZ = 1.f / MZf[2 * b + 1];
    float4 bv = reinterpret_cast<const float4*>(b_buf)[i];
    float4 wv;
    wv.x = __expf(bv.x - Mg) * iZ;
    wv.y = __expf(bv.y - Mg) * iZ;
    wv.z = __expf(bv.z - Mg) * iZ;
    wv.w = __expf(bv.w - Mg) * iZ;
    reinterpret_cast<float4*>(w_out)[i] = wv;
}

extern "C" void kernel_launch(void* const* d_in, const int* in_sizes, int n_in,
                              void* d_out, int out_size, void* d_ws, size_t ws_size,
                              hipStream_t stream)
{
    const float* x = (const float*)d_in[0];
    const float* m = (const float*)d_in[1];
    float* out = (float*)d_out;                 // [B*N] w, then [B*D] s

    // pick partials-per-batch P to fit workspace
    int P = 128;
    auto needBytes = [](int Pv) -> size_t {
        return (size_t)(BB * NN + BB * DD + (size_t)BB * Pv * DD + BB * Pv * 2 + 2 * BB)
               * sizeof(float);
    };
    while (P > 8 && needBytes(P) > ws_size) P >>= 1;

    float* ws       = (float*)d_ws;
    float* b_buf    = ws;
    float* s_buf    = b_buf + BB * NN;
    float* part_sig = s_buf + BB * DD;
    float* part_M   = part_sig + (size_t)BB * P * DD;
    float* part_Z   = part_M + BB * P;
    float* MZf      = part_Z + BB * P;

    // b = 0 and s = 0 (pass 1 with s=0 reproduces the uniform first softmax)
    hipMemsetAsync(ws, 0, (size_t)(BB * NN + BB * DD) * sizeof(float), stream);

    const int rpw = NN / P;
    const int blocksF = BB * P / 4;
    float* s_final = out + BB * NN;

    for (int it = 0; it < 3; ++it) {
        fpass_kernel<false><<<blocksF, 256, 0, stream>>>(
            x, m, s_buf, b_buf, part_sig, part_M, part_Z, P, rpw);
        reduce_kernel<false><<<BB, 1024, 0, stream>>>(
            part_sig, part_M, part_Z, s_buf, (it == 2) ? s_final : nullptr, MZf, P);
    }
    // final b-update + stats for softmax(b)
    fpass_kernel<true><<<blocksF, 256, 0, stream>>>(
        x, m, s_buf, b_buf, part_sig, part_M, part_Z, P, rpw);
    reduce_kernel<true><<<BB, 1024, 0, stream>>>(
        part_sig, part_M, part_Z, s_buf, nullptr, MZf, P);
    w_kernel<<<BB * NN / 1024, 256, 0, stream>>>(b_buf, MZf, out);
}

// Round 6
// 480.431 us; speedup vs baseline: 1.0706x; 1.0706x over previous
//
#include <hip/hip_runtime.h>
#include <math.h>

#define BB 64
#define NN 4096
#define DD 256

typedef _Float16 f16;
typedef f16 f16x4 __attribute__((ext_vector_type(4)));

// ---------------------------------------------------------------------------
// Pass 1: x_tilde = m*x (fp32 read, fp16 write) + unweighted sum partials.
// b=0 => softmax is uniform => sigma_1 = sum(x_tilde)/N. No dots, no exp.
// Each wave owns rowsPerWave consecutive rows; lane i owns columns 4i..4i+3.
// ---------------------------------------------------------------------------
__global__ __launch_bounds__(256) void pass1_kernel(
    const float* __restrict__ x, const float* __restrict__ m,
    f16* __restrict__ xt, float* __restrict__ part_sig,
    float* __restrict__ part_M, float* __restrict__ part_Z,
    int P, int rowsPerWave)
{
    const int lane = threadIdx.x & 63;
    const int wib  = threadIdx.x >> 6;
    const int bpb  = P >> 2;
    const int batch = blockIdx.x / bpb;
    const int p = (blockIdx.x % bpb) * 4 + wib;
    const int n0 = p * rowsPerWave;

    const float4* __restrict__ xr =
        reinterpret_cast<const float4*>(x + ((size_t)batch * NN + n0) * DD) + lane;
    f16x4* __restrict__ xtr =
        reinterpret_cast<f16x4*>(xt + ((size_t)batch * NN + n0) * DD) + lane;
    const float* __restrict__ mrow = m + (size_t)batch * NN + n0;

    float sx = 0.f, sy = 0.f, sz = 0.f, sw = 0.f;

    for (int r0 = 0; r0 < rowsPerWave; r0 += 4) {
        float4 xv0 = xr[(size_t)(r0 + 0) * (DD / 4)];
        float4 xv1 = xr[(size_t)(r0 + 1) * (DD / 4)];
        float4 xv2 = xr[(size_t)(r0 + 2) * (DD / 4)];
        float4 xv3 = xr[(size_t)(r0 + 3) * (DD / 4)];
        const float4 m4 = *reinterpret_cast<const float4*>(mrow + r0);

        float4 t0 = make_float4(m4.x * xv0.x, m4.x * xv0.y, m4.x * xv0.z, m4.x * xv0.w);
        float4 t1 = make_float4(m4.y * xv1.x, m4.y * xv1.y, m4.y * xv1.z, m4.y * xv1.w);
        float4 t2 = make_float4(m4.z * xv2.x, m4.z * xv2.y, m4.z * xv2.z, m4.z * xv2.w);
        float4 t3 = make_float4(m4.w * xv3.x, m4.w * xv3.y, m4.w * xv3.z, m4.w * xv3.w);

        xtr[(size_t)(r0 + 0) * (DD / 4)] = f16x4{(f16)t0.x, (f16)t0.y, (f16)t0.z, (f16)t0.w};
        xtr[(size_t)(r0 + 1) * (DD / 4)] = f16x4{(f16)t1.x, (f16)t1.y, (f16)t1.z, (f16)t1.w};
        xtr[(size_t)(r0 + 2) * (DD / 4)] = f16x4{(f16)t2.x, (f16)t2.y, (f16)t2.z, (f16)t2.w};
        xtr[(size_t)(r0 + 3) * (DD / 4)] = f16x4{(f16)t3.x, (f16)t3.y, (f16)t3.z, (f16)t3.w};

        sx += t0.x + t1.x + t2.x + t3.x;
        sy += t0.y + t1.y + t2.y + t3.y;
        sz += t0.z + t1.z + t2.z + t3.z;
        sw += t0.w + t1.w + t2.w + t3.w;
    }
    reinterpret_cast<float4*>(part_sig + ((size_t)batch * P + p) * DD)[lane] =
        make_float4(sx, sy, sz, sw);
    if (lane == 0) {
        part_M[batch * P + p] = 0.f;                 // uniform logits = 0
        part_Z[batch * P + p] = (float)rowsPerWave;  // sum of exp(0)
    }
}

// ---------------------------------------------------------------------------
// F-pass over fp16 x_tilde: b[n] += dot(s, xt[n]); online-softmax partials
// of logits l = m*b (or l = b for FINAL) with exp-weighted sigma partials.
// 8B/lane loads, 4-row groups, branchless online update.
// ---------------------------------------------------------------------------
template<bool FINAL>
__global__ __launch_bounds__(256) void fpass16_kernel(
    const f16* __restrict__ xt, const float* __restrict__ m,
    const float* __restrict__ s_buf, float* __restrict__ b_buf,
    float* __restrict__ part_sig, float* __restrict__ part_M,
    float* __restrict__ part_Z, int P, int rowsPerWave)
{
    const int lane = threadIdx.x & 63;
    const int wib  = threadIdx.x >> 6;
    const int bpb  = P >> 2;
    const int batch = blockIdx.x / bpb;
    const int p = (blockIdx.x % bpb) * 4 + wib;
    const int n0 = p * rowsPerWave;

    const float4 s4 = reinterpret_cast<const float4*>(s_buf + batch * DD)[lane];
    const f16x4* __restrict__ xr =
        reinterpret_cast<const f16x4*>(xt + ((size_t)batch * NN + n0) * DD) + lane;
    const float* __restrict__ mrow = m + (size_t)batch * NN + n0;
    float* __restrict__ brow = b_buf + (size_t)batch * NN + n0;

    float M = -INFINITY, Z = 0.f;
    float sx = 0.f, sy = 0.f, sz = 0.f, sw = 0.f;

    auto upd = [&](float bn, float mn, const float4& xv) {
        float l = FINAL ? bn : mn * bn;
        float newM = fmaxf(M, l);
        float c = __expf(M - newM);
        float e = __expf(l - newM);
        Z = Z * c + e;
        if (!FINAL) {
            sx = sx * c + e * xv.x;
            sy = sy * c + e * xv.y;
            sz = sz * c + e * xv.z;
            sw = sw * c + e * xv.w;
        }
        M = newM;
    };

    for (int r0 = 0; r0 < rowsPerWave; r0 += 4) {
        f16x4 h0 = xr[(size_t)(r0 + 0) * (DD / 4)];
        f16x4 h1 = xr[(size_t)(r0 + 1) * (DD / 4)];
        f16x4 h2 = xr[(size_t)(r0 + 2) * (DD / 4)];
        f16x4 h3 = xr[(size_t)(r0 + 3) * (DD / 4)];
        const float4 m4 = *reinterpret_cast<const float4*>(mrow + r0);
        const float4 b4 = *reinterpret_cast<const float4*>(brow + r0);

        float4 xv0 = make_float4((float)h0.x, (float)h0.y, (float)h0.z, (float)h0.w);
        float4 xv1 = make_float4((float)h1.x, (float)h1.y, (float)h1.z, (float)h1.w);
        float4 xv2 = make_float4((float)h2.x, (float)h2.y, (float)h2.z, (float)h2.w);
        float4 xv3 = make_float4((float)h3.x, (float)h3.y, (float)h3.z, (float)h3.w);

        float dp0 = xv0.x * s4.x + xv0.y * s4.y + xv0.z * s4.z + xv0.w * s4.w;
        float dp1 = xv1.x * s4.x + xv1.y * s4.y + xv1.z * s4.z + xv1.w * s4.w;
        float dp2 = xv2.x * s4.x + xv2.y * s4.y + xv2.z * s4.z + xv2.w * s4.w;
        float dp3 = xv3.x * s4.x + xv3.y * s4.y + xv3.z * s4.z + xv3.w * s4.w;
        #pragma unroll
        for (int off = 32; off; off >>= 1) {
            dp0 += __shfl_xor(dp0, off, 64);
            dp1 += __shfl_xor(dp1, off, 64);
            dp2 += __shfl_xor(dp2, off, 64);
            dp3 += __shfl_xor(dp3, off, 64);
        }
        // b += s . x_tilde   (x_tilde already includes m)
        float bn0 = b4.x + dp0;
        float bn1 = b4.y + dp1;
        float bn2 = b4.z + dp2;
        float bn3 = b4.w + dp3;
        if (lane == 0)
            *reinterpret_cast<float4*>(brow + r0) = make_float4(bn0, bn1, bn2, bn3);
        upd(bn0, m4.x, xv0);
        upd(bn1, m4.y, xv1);
        upd(bn2, m4.z, xv2);
        upd(bn3, m4.w, xv3);
    }
    if (!FINAL) {
        reinterpret_cast<float4*>(part_sig + ((size_t)batch * P + p) * DD)[lane] =
            make_float4(sx, sy, sz, sw);
    }
    if (lane == 0) {
        part_M[batch * P + p] = M;
        part_Z[batch * P + p] = Z;
    }
}

// ---------------------------------------------------------------------------
// Reduce: combine P wave-partials of one batch with max-rescaling.
// Wave 0 reduces M/Z via shuffles; 1024 threads split the p-loop 4-way.
// !FINAL: sigma = (sum_p c_p * part_sig_p)/Z, squash -> s_buf (and s_out).
// FINAL:  just write (Mg, Zg) for the final softmax.
// ---------------------------------------------------------------------------
template<bool FINAL>
__global__ __launch_bounds__(1024) void reduce_kernel(
    const float* __restrict__ part_sig, const float* __restrict__ part_M,
    const float* __restrict__ part_Z, float* __restrict__ s_buf,
    float* __restrict__ s_out, float* __restrict__ MZf, int P)
{
    const int b = blockIdx.x;
    const int tid = threadIdx.x;
    __shared__ float red[1024];
    __shared__ float csh[128];
    __shared__ float mg_sh, zg_sh;

    if (tid < 64) {
        float M0 = (tid < P) ? part_M[b * P + tid] : -INFINITY;
        float M1 = (tid + 64 < P) ? part_M[b * P + tid + 64] : -INFINITY;
        float Mm = fmaxf(M0, M1);
        #pragma unroll
        for (int off = 32; off; off >>= 1) Mm = fmaxf(Mm, __shfl_xor(Mm, off, 64));
        float c0 = (tid < P) ? expf(M0 - Mm) : 0.f;
        float c1 = (tid + 64 < P) ? expf(M1 - Mm) : 0.f;
        if (tid < P) csh[tid] = c0;
        if (tid + 64 < P) csh[tid + 64] = c1;
        float Zs = ((tid < P) ? part_Z[b * P + tid] : 0.f) * c0
                 + ((tid + 64 < P) ? part_Z[b * P + tid + 64] : 0.f) * c1;
        #pragma unroll
        for (int off = 32; off; off >>= 1) Zs += __shfl_xor(Zs, off, 64);
        if (tid == 0) { mg_sh = Mm; zg_sh = Zs; }
    }
    __syncthreads();

    if (FINAL) {
        if (tid == 0) { MZf[2 * b] = mg_sh; MZf[2 * b + 1] = zg_sh; }
        return;
    }

    const int q = tid >> 8;       // 0..3: p-residue class
    const int d = tid & 255;      // feature dim
    float sig = 0.f;
    #pragma unroll 4
    for (int k = q; k < P; k += 4)
        sig += csh[k] * part_sig[((size_t)b * P + k) * DD + d];
    red[tid] = sig;
    __syncthreads();

    if (tid < 256) {
        sig = red[tid] + red[tid + 256] + red[tid + 512] + red[tid + 768];
        sig /= zg_sh;
        red[tid] = sig * sig;
    }
    __syncthreads();
    for (int s = 128; s > 0; s >>= 1) {
        if (tid < s) red[tid] += red[tid + s];
        __syncthreads();
    }
    if (tid < 256) {
        float n2 = red[0];
        float nrm = sqrtf(n2);
        float scale = n2 / (1.f + n2) / (nrm + 1e-8f);   // squash
        float sv = scale * sig;
        s_buf[b * DD + tid] = sv;
        if (s_out) s_out[b * DD + tid] = sv;
    }
}

// ---------------------------------------------------------------------------
// Final w = exp(b - M)/Z  (softmax over N, logits = b), float4-vectorized.
// ---------------------------------------------------------------------------
__global__ __launch_bounds__(256) void w_kernel(
    const float* __restrict__ b_buf, const float* __restrict__ MZf,
    float* __restrict__ w_out)
{
    int i = blockIdx.x * 256 + threadIdx.x;   // over B*N/4 float4s
    int b = i >> 10;                          // N/4 = 1024 float4 per batch
    float Mg = MZf[2 * b];
    float iZ = 1.f / MZf[2 * b + 1];
    float4 bv = reinterpret_cast<const float4*>(b_buf)[i];
    float4 wv;
    wv.x = __expf(bv.x - Mg) * iZ;
    wv.y = __expf(bv.y - Mg) * iZ;
    wv.z = __expf(bv.z - Mg) * iZ;
    wv.w = __expf(bv.w - Mg) * iZ;
    reinterpret_cast<float4*>(w_out)[i] = wv;
}

extern "C" void kernel_launch(void* const* d_in, const int* in_sizes, int n_in,
                              void* d_out, int out_size, void* d_ws, size_t ws_size,
                              hipStream_t stream)
{
    const float* x = (const float*)d_in[0];
    const float* m = (const float*)d_in[1];
    float* out = (float*)d_out;                 // [B*N] w, then [B*D] s

    const size_t xtElems = (size_t)BB * NN * DD;          // fp16 x_tilde copy
    // pick partials-per-batch P to fit workspace (xt + fp32 scratch)
    int P = 128;
    auto needBytes = [&](int Pv) -> size_t {
        return xtElems * sizeof(f16) +
               (size_t)(BB * NN + BB * DD + (size_t)BB * Pv * DD + BB * Pv * 2 + 2 * BB)
               * sizeof(float);
    };
    while (P > 8 && needBytes(P) > ws_size) P >>= 1;

    f16*   xt       = (f16*)d_ws;
    float* b_buf    = (float*)(xt + xtElems);
    float* s_buf    = b_buf + BB * NN;
    float* part_sig = s_buf + BB * DD;
    float* part_M   = part_sig + (size_t)BB * P * DD;
    float* part_Z   = part_M + BB * P;
    float* MZf      = part_Z + BB * P;

    // b = 0 (s_buf is fully written by reduce before first use)
    hipMemsetAsync(b_buf, 0, (size_t)(BB * NN) * sizeof(float), stream);

    const int rpw = NN / P;
    const int blocksF = BB * P / 4;
    float* s_final = out + BB * NN;

    // Pass 1: transform + uniform-weight sum  -> sigma_1
    pass1_kernel<<<blocksF, 256, 0, stream>>>(
        x, m, xt, part_sig, part_M, part_Z, P, rpw);
    reduce_kernel<false><<<BB, 1024, 0, stream>>>(
        part_sig, part_M, part_Z, s_buf, nullptr, MZf, P);

    // Passes 2..3: b-update + next sigma (fp16 reads)
    for (int it = 1; it < 3; ++it) {
        fpass16_kernel<false><<<blocksF, 256, 0, stream>>>(
            xt, m, s_buf, b_buf, part_sig, part_M, part_Z, P, rpw);
        reduce_kernel<false><<<BB, 1024, 0, stream>>>(
            part_sig, part_M, part_Z, s_buf, (it == 2) ? s_final : nullptr, MZf, P);
    }
    // Pass 4: final b-update + stats for softmax(b)
    fpass16_kernel<true><<<blocksF, 256, 0, stream>>>(
        xt, m, s_buf, b_buf, part_sig, part_M, part_Z, P, rpw);
    reduce_kernel<true><<<BB, 1024, 0, stream>>>(
        part_sig, part_M, part_Z, s_buf, nullptr, MZf, P);
    w_kernel<<<BB * NN / 1024, 256, 0, stream>>>(b_buf, MZf, out);
}